// Round 17
// baseline (116.270 us; speedup 1.0000x reference)
//
#include <hip/hip_runtime.h>

#define NREL 8192
#define RD   256
#define RSHIFT 16.0f   // constant softmax shift: >= max(right) with huge margin

typedef float f32x4 __attribute__((ext_vector_type(4)));
typedef short s16x8 __attribute__((ext_vector_type(8)));
typedef unsigned int  u32;
typedef unsigned short u16;
typedef unsigned long long u64;
typedef u32 u32x4 __attribute__((ext_vector_type(4)));

__device__ __forceinline__ u16 f2bf(float f) {
    u32 b = __float_as_uint(f);
    return (u16)((b + 0x7FFFu + ((b >> 16) & 1u)) >> 16);   // RNE
}
__device__ __forceinline__ u32 pk_bf16(float lo, float hi) {
    u32 r;
    asm("v_cvt_pk_bf16_f32 %0, %1, %2" : "=v"(r) : "v"(lo), "v"(hi));
    return r;   // low16 = bf16(lo), high16 = bf16(hi), RNE
}

// ---------------- K1: fused {u_left/u_right} + {Bf fragment repack} ---------
__global__ __launch_bounds__(256) void k_prep_bf(
    const float* __restrict__ W, const float* __restrict__ wl,
    const float* __restrict__ wr, float* __restrict__ ul,
    float* __restrict__ ur, const float* __restrict__ R,
    u32* __restrict__ Bf)
{
    __shared__ float sL[256], sR[256];
    const int t = threadIdx.x;
    if (blockIdx.x < 32) {
        const int d = blockIdx.x * 16 + (t & 15);
        float aL = 0.f, aR = 0.f;
        for (int h = (t >> 4); h < 256; h += 16) {
            float w = W[h * 512 + d];
            aL += w * wl[h];
            aR += w * wr[h];
        }
        sL[t] = aL; sR[t] = aR;
        __syncthreads();
        if (t < 16) {
            float xL = 0.f, xR = 0.f;
            for (int g = 0; g < 16; g++) { xL += sL[g * 16 + t]; xR += sR[g * 16 + t]; }
            ul[blockIdx.x * 16 + t] = xL;
            ur[blockIdx.x * 16 + t] = xR;
        }
        return;
    }
    if (!Bf) return;
    const int b     = blockIdx.x - 32;
    const int jt    = b >> 1;
    const int fbase = (b & 1) * 1024;
    #pragma unroll
    for (int rep = 0; rep < 4; rep++) {
        const int f    = fbase + rep * 256 + t;   // 0..2047
        const int kk   = f >> 10;
        const int cg   = (f >> 6) & 15;
        const int lane = f & 63;
        const int lq   = lane >> 4;
        const int l15  = lane & 15;
        const int j0   = (jt << 6) + kk * 32 + lq * 8;
        const int n    = cg * 16 + l15;
        const float* src = R + (size_t)j0 * RD + n;
        float v[8];
        #pragma unroll
        for (int e = 0; e < 8; e++) v[e] = src[(size_t)e * RD];
        u32x4 w;
        w.x = pk_bf16(v[0], v[1]);
        w.y = pk_bf16(v[2], v[3]);
        w.z = pk_bf16(v[4], v[5]);
        w.w = pk_bf16(v[6], v[7]);
        *(u32x4*)(Bf + ((size_t)jt * 2048 + f) * 4) = w;
    }
}

// ---------------- K2: left/right rows (no atomics) --------------------------
__global__ __launch_bounds__(256) void k_lr(
    const float* __restrict__ ctx, const float* __restrict__ ul,
    const float* __restrict__ ur, const float* __restrict__ bl,
    const float* __restrict__ br, float* __restrict__ left,
    float* __restrict__ right)
{
    const int lane = threadIdx.x & 63;
    const int row  = blockIdx.x * 4 + (threadIdx.x >> 6);
    const f32x4* cv = (const f32x4*)(ctx + (size_t)row * 512);
    const f32x4* uv = (const f32x4*)ul;
    const f32x4* vv = (const f32x4*)ur;
    f32x4 c0 = cv[lane], c1 = cv[lane + 64];
    f32x4 u0 = uv[lane], u1 = uv[lane + 64];
    f32x4 v0 = vv[lane], v1 = vv[lane + 64];
    float dl = c0.x*u0.x + c0.y*u0.y + c0.z*u0.z + c0.w*u0.w
             + c1.x*u1.x + c1.y*u1.y + c1.z*u1.z + c1.w*u1.w;
    float dr = c0.x*v0.x + c0.y*v0.y + c0.z*v0.z + c0.w*v0.w
             + c1.x*v1.x + c1.y*v1.y + c1.z*v1.z + c1.w*v1.w;
    #pragma unroll
    for (int o = 1; o < 64; o <<= 1) { dl += __shfl_xor(dl, o); dr += __shfl_xor(dr, o); }
    if (lane == 0) {
        left[row]  = dl + bl[0];
        right[row] = dr + br[0];
    }
}

// ---------------- K3f: FUSED masked-softmax attention, 4-tile groups --------
// 512 thr (8 waves), 64-row blocks, K-split S=4. Per phase: one GROUP of
// 4 tiles (256 cols) -> each thread loads 64 B CONTIGUOUS adj per row
// (1 KB/row per 16 threads) -> 4x fewer DRAM page activations at the 32 KB
// row stride. 2 barriers per 4 tiles (halved). Group-order rotation spreads
// channels. adj/right single-buffered (cover = full 4-tile MFMA phase).
template<int S>
__global__ __launch_bounds__(512) void k_attn_f(
    const float* __restrict__ adj, const s16x8* __restrict__ Bf,
    const float* __restrict__ left, const float* __restrict__ right,
    float* __restrict__ pnum, float* __restrict__ pden)
{
    __shared__ u32 Pt[4 * 2048];    // 4 tile buffers, 64x64 bf16 swizzled, 32 KB
    constexpr int NT = 128 / S;     // tiles per split (32)
    constexpr int NG = NT / 4;      // groups per split (8)

    const int tid  = threadIdx.x;
    const int lane = tid & 63;
    const int wv   = tid >> 6;          // 0..7
    const int l15  = lane & 15;
    const int lq   = lane >> 4;
    const int s      = (int)(blockIdx.x % (unsigned)S);
    const int rowblk = (int)(blockIdx.x / (unsigned)S) * 64;
    const int jt0 = s * NT;
    const int rot = (int)(blockIdx.x & (NG - 1));

    const int pr = tid >> 4;        // 0..31 (rows pr, pr+32)
    const int pq = tid & 15;        // 16 consecutive cols: pq*16 .. +15 in group

    const float lft0 = left[rowblk + pr];
    const float lft1 = left[rowblk + pr + 32];
    float z;
    z = lft0 + RSHIFT; const float m0 = fmaxf(z, 0.2f * z);
    z = lft1 + RSHIFT; const float m1 = fmaxf(z, 0.2f * z);

    f32x4 acc[4][2];
    #pragma unroll
    for (int i = 0; i < 4; i++) { acc[i][0] = (f32x4)0.f; acc[i][1] = (f32x4)0.f; }
    float dp0 = 0.f, dp1 = 0.f;

    const f32x4* adjv = (const f32x4*)adj;
    const f32x4* rv4  = (const f32x4*)right;
    const size_t arow0 = (size_t)(rowblk + pr) * 2048;
    const size_t arow1 = (size_t)(rowblk + pr + 32) * 2048;

    const u32 bc  = (u32)(pq & 3) * 8;          // u32 col base within tile
    const u32 swz = ((u32)pr & 7) << 2;
    u32* const Pb = Pt + (size_t)(pq >> 2) * 2048;   // this thread's tile buffer

    #define GBASE(g) (jt0 + (((g) + rot) & (NG - 1)) * 4)

    // ---- prologue: stage group 0 (adj: 64 B contiguous/row/thread) + B tile 0
    f32x4 a0[4], a1[4], rr[4];
    {
        const int jg = GBASE(0);
        #pragma unroll
        for (int q = 0; q < 4; q++) {
            a0[q] = adjv[arow0 + jg * 16 + pq * 4 + q];
            a1[q] = adjv[arow1 + jg * 16 + pq * 4 + q];
            rr[q] = rv4[jg * 16 + pq * 4 + q];
        }
    }
    s16x8 bA[2][2], bB[2][2];
    #pragma unroll
    for (int kk = 0; kk < 2; kk++)
        #pragma unroll
        for (int ct = 0; ct < 2; ct++)
            bA[kk][ct] = Bf[(size_t)GBASE(0) * 2048 + kk * 1024
                            + (wv * 2 + ct) * 64 + lane];

    #define BLOAD(DST, JT)                                                     \
        _Pragma("unroll")                                                      \
        for (int kk = 0; kk < 2; kk++)                                         \
            _Pragma("unroll")                                                  \
            for (int ct = 0; ct < 2; ct++)                                     \
                DST[kk][ct] = Bf[(size_t)(JT) * 2048 + kk * 1024               \
                                 + (wv * 2 + ct) * 64 + lane];

    #define MFMA_TILE(TT, BSLOT)                                               \
        {                                                                      \
            const u16* Pu = (const u16*)(Pt + (TT) * 2048);                    \
            _Pragma("unroll")                                                  \
            for (int kk = 0; kk < 2; kk++) {                                   \
                s16x8 af[4];                                                   \
                _Pragma("unroll")                                              \
                for (int rt = 0; rt < 4; rt++) {                               \
                    const int row = rt * 16 + l15;                             \
                    const int us  = row * 64                                   \
                                  + ((kk * 32 + lq * 8) ^ ((row & 7) << 3));   \
                    af[rt] = *(const s16x8*)(Pu + us);                         \
                }                                                              \
                _Pragma("unroll")                                              \
                for (int ct = 0; ct < 2; ct++)                                 \
                    _Pragma("unroll")                                          \
                    for (int rt = 0; rt < 4; rt++)                             \
                        acc[rt][ct] = __builtin_amdgcn_mfma_f32_16x16x32_bf16( \
                            af[rt], BSLOT[kk][ct], acc[rt][ct], 0, 0, 0);      \
            }                                                                  \
        }

    for (int g = 0; g < NG; g++) {
        const int jgc = GBASE(g);
        const int jgn = GBASE((g + 1 < NG) ? g + 1 : 0);

        // ---- P-gen: 2 rows x 16 cols -> this thread's tile buffer
        #pragma unroll
        for (int q = 0; q < 4; q++) {
            float pa[4], pb[4];
            #pragma unroll
            for (int e = 0; e < 4; e++) {
                const float r = rr[q][e];
                float z0 = lft0 + r; float s0 = fmaxf(z0, 0.2f * z0);
                pa[e] = a0[q][e] * __expf(s0 - m0);
                float z1 = lft1 + r; float s1 = fmaxf(z1, 0.2f * z1);
                pb[e] = a1[q][e] * __expf(s1 - m1);
            }
            dp0 += pa[0] + pa[1] + pa[2] + pa[3];
            dp1 += pb[0] + pb[1] + pb[2] + pb[3];
            const u32 i0 = (u32)pr * 32 + ((bc + q * 2) ^ swz);
            Pb[i0]        = pk_bf16(pa[0], pa[1]);
            Pb[i0 + 1]    = pk_bf16(pa[2], pa[3]);
            Pb[i0 + 1024] = pk_bf16(pb[0], pb[1]);
            Pb[i0 + 1025] = pk_bf16(pb[2], pb[3]);
        }

        asm volatile("s_waitcnt lgkmcnt(0)" ::: "memory");
        __builtin_amdgcn_s_barrier();

        // ---- issue next-group adj/right loads (ride across the MFMA phase)
        #pragma unroll
        for (int q = 0; q < 4; q++) {
            a0[q] = adjv[arow0 + jgn * 16 + pq * 4 + q];
            a1[q] = adjv[arow1 + jgn * 16 + pq * 4 + q];
            rr[q] = rv4[jgn * 16 + pq * 4 + q];
        }

        // ---- MFMA the 4 tiles; B-frags 1 tile ahead (L2-resident)
        BLOAD(bB, jgc + 1);  MFMA_TILE(0, bA);
        BLOAD(bA, jgc + 2);  MFMA_TILE(1, bB);
        BLOAD(bB, jgc + 3);  MFMA_TILE(2, bA);
        BLOAD(bA, jgn);      MFMA_TILE(3, bB);

        asm volatile("s_waitcnt lgkmcnt(0)" ::: "memory");
        __builtin_amdgcn_s_barrier();
    }
    #undef GBASE
    #undef BLOAD
    #undef MFMA_TILE

    // ---- partial denominators
    #pragma unroll
    for (int o = 1; o < 16; o <<= 1) { dp0 += __shfl_xor(dp0, o); dp1 += __shfl_xor(dp1, o); }
    if (pq == 0) {
        pden[(size_t)s * NREL + rowblk + pr]      = dp0;
        pden[(size_t)s * NREL + rowblk + pr + 32] = dp1;
    }
    // ---- partial numerators
    float* pn = pnum + (size_t)s * NREL * RD;
    #pragma unroll
    for (int rt = 0; rt < 4; rt++)
        #pragma unroll
        for (int ct = 0; ct < 2; ct++)
            #pragma unroll
            for (int r = 0; r < 4; r++) {
                const int row = rt * 16 + lq * 4 + r;
                pn[(size_t)(rowblk + row) * RD + (wv * 32 + ct * 16 + l15)] =
                    acc[rt][ct][r];
            }
}

// ---------------- K4: reduce partials: out = relu(sum num / sum den) --------
template<int S>
__global__ __launch_bounds__(256) void k_red(
    const float* __restrict__ pnum, const float* __restrict__ pden,
    float* __restrict__ out)
{
    const int idx = blockIdx.x * 256 + threadIdx.x;   // f32x4 index
    const int row = idx >> 6;
    float den = 0.f;
    #pragma unroll
    for (int s = 0; s < S; s++) den += pden[(size_t)s * NREL + row];
    const f32x4* pn4 = (const f32x4*)pnum;
    f32x4 a = (f32x4)0.f;
    #pragma unroll
    for (int s = 0; s < S; s++) a += pn4[(size_t)s * (NREL * RD / 4) + idx];
    f32x4 r;
    r.x = fmaxf(a.x / den, 0.f);
    r.y = fmaxf(a.y / den, 0.f);
    r.z = fmaxf(a.z / den, 0.f);
    r.w = fmaxf(a.w / den, 0.f);
    ((f32x4*)out)[idx] = r;
}

// ---------------- legacy fallback (tiny ws): direct adj, no precompute ------
__global__ __launch_bounds__(512) void k_attn_leg(
    const float* __restrict__ adj, const float* __restrict__ rel,
    const float* __restrict__ left, const float* __restrict__ right,
    float* __restrict__ outp)
{
    __shared__ u32   Pl[64 * 32];
    __shared__ float dnm[64];
    const int tid  = threadIdx.x;
    const int lane = tid & 63;
    const int wv   = tid >> 6;
    const int l15  = lane & 15;
    const int lq   = lane >> 4;
    const int rowblk = blockIdx.x * 64;
    const int pr = tid >> 4, pq = tid & 15;
    const float lft0 = left[rowblk + pr];
    const float lft1 = left[rowblk + pr + 32];
    float z;
    z = lft0 + RSHIFT; const float m0 = fmaxf(z, 0.2f * z);
    z = lft1 + RSHIFT; const float m1 = fmaxf(z, 0.2f * z);
    f32x4 acc[4][2];
    #pragma unroll
    for (int i = 0; i < 4; i++) { acc[i][0] = (f32x4)0.f; acc[i][1] = (f32x4)0.f; }
    float dp0 = 0.f, dp1 = 0.f;
    const f32x4* adjv = (const f32x4*)adj;
    const f32x4* rv4  = (const f32x4*)right;
    const size_t arow0 = (size_t)(rowblk + pr) * 2048;
    const size_t arow1 = (size_t)(rowblk + pr + 32) * 2048;
    const int n0 = wv * 32 + l15;
    const u32 widx0 = (u32)pr * 32 + (((u32)pq * 2) ^ (((u32)pr & 7) << 2));
    const u32 widx1 = widx0 + 1024;
    for (int jb = 0; jb < NREL; jb += 64) {
        f32x4 a0 = adjv[arow0 + (jb >> 2) + pq];
        f32x4 a1 = adjv[arow1 + (jb >> 2) + pq];
        f32x4 rv = rv4[(jb >> 2) + pq];
        s16x8 bc[2][2];
        #pragma unroll
        for (int kk = 0; kk < 2; kk++)
            #pragma unroll
            for (int ct = 0; ct < 2; ct++) {
                const float* rp = rel + (size_t)(jb + kk * 32 + lq * 8) * RD
                                      + (n0 + ct * 16);
                s16x8 b;
                #pragma unroll
                for (int e = 0; e < 8; e++) b[e] = (short)f2bf(rp[(size_t)e * RD]);
                bc[kk][ct] = b;
            }
        float pa[4], pb[4];
        #pragma unroll
        for (int e = 0; e < 4; e++) {
            const float r = rv[e];
            float z0 = lft0 + r; float s0 = fmaxf(z0, 0.2f * z0);
            pa[e] = a0[e] * __expf(s0 - m0);
            float z1 = lft1 + r; float s1 = fmaxf(z1, 0.2f * z1);
            pb[e] = a1[e] * __expf(s1 - m1);
        }
        dp0 += pa[0] + pa[1] + pa[2] + pa[3];
        dp1 += pb[0] + pb[1] + pb[2] + pb[3];
        Pl[widx0]     = pk_bf16(pa[0], pa[1]);
        Pl[widx0 + 1] = pk_bf16(pa[2], pa[3]);
        Pl[widx1]     = pk_bf16(pb[0], pb[1]);
        Pl[widx1 + 1] = pk_bf16(pb[2], pb[3]);
        __syncthreads();
        #pragma unroll
        for (int kk = 0; kk < 2; kk++) {
            s16x8 af[4];
            #pragma unroll
            for (int rt = 0; rt < 4; rt++) {
                const int row = rt * 16 + l15;
                const int us  = row * 64 + ((kk * 32 + lq * 8) ^ ((row & 7) << 3));
                af[rt] = *(const s16x8*)((const u16*)Pl + us);
            }
            #pragma unroll
            for (int ct = 0; ct < 2; ct++)
                #pragma unroll
                for (int rt = 0; rt < 4; rt++)
                    acc[rt][ct] = __builtin_amdgcn_mfma_f32_16x16x32_bf16(
                        af[rt], bc[kk][ct], acc[rt][ct], 0, 0, 0);
        }
        __syncthreads();
    }
    #pragma unroll
    for (int o = 1; o < 16; o <<= 1) { dp0 += __shfl_xor(dp0, o); dp1 += __shfl_xor(dp1, o); }
    if (pq == 0) { dnm[pr] = dp0; dnm[pr + 32] = dp1; }
    __syncthreads();
    #pragma unroll
    for (int rt = 0; rt < 4; rt++)
        #pragma unroll
        for (int ct = 0; ct < 2; ct++)
            #pragma unroll
            for (int r = 0; r < 4; r++) {
                const int row = rt * 16 + lq * 4 + r;
                float v = acc[rt][ct][r] / dnm[row];
                outp[(size_t)(rowblk + row) * RD + (wv * 32 + ct * 16 + l15)] =
                    fmaxf(v, 0.f);
            }
}

extern "C" void kernel_launch(void* const* d_in, const int* in_sizes, int n_in,
                              void* d_out, int out_size, void* d_ws, size_t ws_size,
                              hipStream_t stream)
{
    const float* relation = (const float*)d_in[0];
    const float* context  = (const float*)d_in[1];
    const float* adj      = (const float*)d_in[2];
    const float* W        = (const float*)d_in[3];
    const float* wl       = (const float*)d_in[4];
    const float* bl       = (const float*)d_in[5];
    const float* wr       = (const float*)d_in[6];
    const float* br       = (const float*)d_in[7];
    float* out = (float*)d_out;

    float* wsf   = (float*)d_ws;
    float* ul    = wsf;
    float* ur    = wsf + 512;
    float* left  = wsf + 1024;
    float* right = wsf + 1024 + 8192;
    const size_t hdr  = 81920;
    const size_t bf_b = (size_t)NREL * RD * 2;              // 4 MB fragments
    u32* Bf   = (u32*)((char*)d_ws + hdr);
    float* pnum = (float*)((char*)d_ws + hdr + bf_b);

    const int S = 4;
    const size_t need = hdr + bf_b
                      + (size_t)S * NREL * RD * 4 + (size_t)S * NREL * 4;

    if (ws_size >= need) {
        float* pden = pnum + (size_t)S * NREL * RD;
        hipLaunchKernelGGL(k_prep_bf, dim3(288), dim3(256), 0, stream,
                           W, wl, wr, ul, ur, relation, Bf);
        hipLaunchKernelGGL(k_lr, dim3(2048), dim3(256), 0, stream,
                           context, ul, ur, bl, br, left, right);
        hipLaunchKernelGGL((k_attn_f<4>), dim3(128 * 4), dim3(512), 0, stream,
                           adj, (const s16x8*)Bf, left, right, pnum, pden);
        hipLaunchKernelGGL((k_red<4>), dim3(2048), dim3(256), 0, stream,
                           pnum, pden, out);
    } else {
        hipLaunchKernelGGL(k_prep_bf, dim3(32), dim3(256), 0, stream,
                           W, wl, wr, ul, ur, relation, (u32*)nullptr);
        hipLaunchKernelGGL(k_lr, dim3(2048), dim3(256), 0, stream,
                           context, ul, ur, bl, br, left, right);
        hipLaunchKernelGGL(k_attn_leg, dim3(128), dim3(512), 0, stream,
                           adj, relation, left, right, out);
    }
}